// Round 15
// baseline (200.372 us; speedup 1.0000x reference)
//
#include <hip/hip_runtime.h>
#include <hip/hip_fp16.h>

// 2-layer GCN, CSR-gather formulation (no float atomics).
// A_norm·(x@W1) = (A_norm·x)@W1 -> layer-1 aggregation in 12-ch space.
// CSR built by two-level LDS bucket sort (run-coalesced writes; scattered
// single-pass fill measured sector-bound at 64B/edge in r4/r7/r8).
// bbuf packed: (row<<7)|local_col (row < 2^17). rs payload = row only.
// RACE LESSON (r11): gather source values (dinv/x) must come from a PRIOR kernel.
// LAYOUT LESSON (r13): channel-slicing h2 trades traffic for 3x instructions.
// L2 LESSON (r15): protect gather2's h2 working set with nt out-stores/rs-loads.
// x and h2 in fp16 (measured safe r8-r14). MLP fused per 64-node tile.

#define IN_CH 12
#define HID 128
#define OUTC 64
#define PADK 132   // hidden-tile row stride in floats (breaks pow2 bank stride)
#define BSH 7      // bucket = 128 dest nodes
#define NBMAX 1024 // supports N <= 131072
#define CHUNK 4096 // edges per k_bucket block
#define SORTMAX 4096

// fused init: zero bcnt + convert x -> fp16
__global__ void k_init(int* __restrict__ bcnt, int nb,
                       const float* __restrict__ x, __half* __restrict__ x16, int n) {
    int i = blockIdx.x * blockDim.x + threadIdx.x;
    if (i < nb) bcnt[i] = 0;
    if (i < n) x16[i] = __float2half(x[i]);
}

// ---- CSR build pass 1: bucket histogram (LDS-privatized) ----
__global__ __launch_bounds__(256) void k_bhist(
    const int* __restrict__ col, int* __restrict__ bcnt, int E, int NB) {
    __shared__ int lh[NBMAX];
    int t = threadIdx.x;
    for (int i = t; i < NB; i += 256) lh[i] = 0;
    __syncthreads();
    int base = blockIdx.x * CHUNK;
    int end = min(base + CHUNK, E);
    for (int e = base + t; e < end; e += 256)
        atomicAdd(&lh[col[e] >> BSH], 1);
    __syncthreads();
    for (int i = t; i < NB; i += 256)
        if (lh[i]) atomicAdd(&bcnt[i], lh[i]);
}

// ---- pass 2: scan bucket counts -> bstart, gcur; also start[N]=E ----
__global__ __launch_bounds__(256) void k_bscan(
    const int* __restrict__ bcnt, int* __restrict__ bstart,
    int* __restrict__ gcur, int* __restrict__ startN, int E, int NB) {
    __shared__ int part[256];
    int t = threadIdx.x;
    int v[4]; int s = 0;
#pragma unroll
    for (int j = 0; j < 4; ++j) { int b = t * 4 + j; v[j] = (b < NB) ? bcnt[b] : 0; s += v[j]; }
    part[t] = s;
    __syncthreads();
    for (int off = 1; off < 256; off <<= 1) {
        int u = (t >= off) ? part[t - off] : 0;
        __syncthreads();
        part[t] += u;
        __syncthreads();
    }
    int base = (t > 0) ? part[t - 1] : 0;
#pragma unroll
    for (int j = 0; j < 4; ++j) {
        int b = t * 4 + j;
        if (b < NB) { bstart[b] = base; gcur[b] = base; }
        base += v[j];
    }
    if (t == 255) bstart[NB] = base;  // == E
    if (t == 0) *startN = E;          // start[N] = E
}

// ---- pass 3: LDS-staged bucket append; writes packed (row<<7)|lcol ----
__global__ __launch_bounds__(256) void k_bucket(
    const int* __restrict__ row, const int* __restrict__ col,
    int* __restrict__ gcur, int* __restrict__ bbuf, int E, int NB) {
    __shared__ int lh[NBMAX], lstart[NBMAX], lcur[NBMAX], gb[NBMAX];
    __shared__ int part[256];
    __shared__ int2 lbuf[CHUNK];  // 32 KiB
    int t = threadIdx.x;
    for (int i = t; i < NB; i += 256) lh[i] = 0;
    __syncthreads();
    int base0 = blockIdx.x * CHUNK;
    int end = min(base0 + CHUNK, E);
    for (int e = base0 + t; e < end; e += 256)
        atomicAdd(&lh[col[e] >> BSH], 1);
    __syncthreads();
    int v[4]; int s = 0;
#pragma unroll
    for (int j = 0; j < 4; ++j) { int b = t * 4 + j; v[j] = (b < NB) ? lh[b] : 0; s += v[j]; }
    part[t] = s;
    __syncthreads();
    for (int off = 1; off < 256; off <<= 1) {
        int u = (t >= off) ? part[t - off] : 0;
        __syncthreads();
        part[t] += u;
        __syncthreads();
    }
    int pb = (t > 0) ? part[t - 1] : 0;
#pragma unroll
    for (int j = 0; j < 4; ++j) {
        int b = t * 4 + j;
        if (b < NB) lstart[b] = pb;
        pb += v[j];
    }
    __syncthreads();
    for (int i = t; i < NB; i += 256) {
        int c = lh[i];
        gb[i] = c ? atomicAdd(&gcur[i], c) : 0;
        lcur[i] = lstart[i];
    }
    __syncthreads();
    for (int e = base0 + t; e < end; e += 256) {
        int c = col[e];
        int p = atomicAdd(&lcur[c >> BSH], 1);
        lbuf[p] = make_int2(row[e], c);
    }
    __syncthreads();
    int cN = end - base0;
    for (int i = t; i < cN; i += 256) {
        int2 rc = lbuf[i];
        int b = rc.y >> BSH;
        bbuf[gb[b] + (i - lstart[b])] = (rc.x << BSH) | (rc.y & 127);
    }
}

// ---- pass 4: per-bucket CSR: start/dinv + LDS sort -> coalesced rs write ----
__global__ __launch_bounds__(256) void k_csr(
    const int* __restrict__ bstart, const int* __restrict__ bbuf,
    int* __restrict__ start, float* __restrict__ dinv,
    int* __restrict__ rs, int N) {
    int me = blockIdx.x;
    int lo = me << BSH;
    int bs = bstart[me], be = bstart[me + 1];
    int cntb = be - bs;
    __shared__ int lh[128], lsc[128];
    __shared__ int lsort[SORTMAX];  // 16 KiB
    int t = threadIdx.x;
    bool lds_ok = (cntb <= SORTMAX);
    if (t < 128) lh[t] = 0;
    __syncthreads();
    for (int i = t; i < cntb; i += 256)
        atomicAdd(&lh[bbuf[bs + i] & 127], 1);
    __syncthreads();
    if (t < 128) lsc[t] = lh[t];
    __syncthreads();
    for (int off = 1; off < 128; off <<= 1) {
        int u = (t < 128 && t >= off) ? lsc[t - off] : 0;
        __syncthreads();
        if (t < 128) lsc[t] += u;
        __syncthreads();
    }
    if (t < 128) {
        int excl = lsc[t] - lh[t];
        int n = lo + t;
        if (n < N) {
            start[n] = bs + excl;
            dinv[n] = rsqrtf((float)lh[t] + 1.0f);
        }
        lsc[t] = excl;  // reuse as cursor
    }
    __syncthreads();
    for (int i = t; i < cntb; i += 256) {
        int v = bbuf[bs + i];
        int p = atomicAdd(&lsc[v & 127], 1);
        int r = v >> BSH;
        if (lds_ok) lsort[p] = r; else rs[bs + p] = r;
    }
    __syncthreads();
    if (lds_ok)  // coalesced rs write-out
        for (int i = t; i < cntb; i += 256) rs[bs + i] = lsort[i];
}

// ---- layer 1 gather: aggx = A_norm·x (12 ch, fp16 x, 8-deep pipeline) ----
__global__ __launch_bounds__(192) void k_gather_x(
    const int* __restrict__ start, const float* __restrict__ dinv,
    const int* __restrict__ rs, const __half* __restrict__ x16,
    float* __restrict__ aggx, int N) {
    int ln = threadIdx.x / 12;
    int c  = threadIdx.x % 12;
    int n  = blockIdx.x * 16 + ln;
    if (n >= N) return;
    float dv = dinv[n];
    int s0 = start[n], k = start[n + 1] - s0;
    float acc = __half2float(x16[(size_t)n * IN_CH + c]) * dv * dv;
    int j = 0;
    for (; j + 8 <= k; j += 8) {
        int r[8];
#pragma unroll
        for (int q = 0; q < 8; ++q) r[q] = __builtin_nontemporal_load(rs + s0 + j + q);
        float nm[8], vv[8];
#pragma unroll
        for (int q = 0; q < 8; ++q) nm[q] = dinv[r[q]] * dv;
#pragma unroll
        for (int q = 0; q < 8; ++q) vv[q] = __half2float(x16[(size_t)r[q] * IN_CH + c]);
#pragma unroll
        for (int q = 0; q < 8; ++q) acc = fmaf(vv[q], nm[q], acc);
    }
    for (; j + 4 <= k; j += 4) {
        int r0 = rs[s0 + j], r1 = rs[s0 + j + 1], r2 = rs[s0 + j + 2], r3 = rs[s0 + j + 3];
        float n0 = dinv[r0] * dv, n1 = dinv[r1] * dv, n2 = dinv[r2] * dv, n3 = dinv[r3] * dv;
        float v0 = __half2float(x16[(size_t)r0 * IN_CH + c]);
        float v1 = __half2float(x16[(size_t)r1 * IN_CH + c]);
        float v2 = __half2float(x16[(size_t)r2 * IN_CH + c]);
        float v3 = __half2float(x16[(size_t)r3 * IN_CH + c]);
        acc = fmaf(v0, n0, acc); acc = fmaf(v1, n1, acc);
        acc = fmaf(v2, n2, acc); acc = fmaf(v3, n3, acc);
    }
    for (; j < k; ++j) {
        int r = rs[s0 + j];
        acc = fmaf(__half2float(x16[(size_t)r * IN_CH + c]), dinv[r] * dv, acc);
    }
    aggx[(size_t)n * IN_CH + c] = acc;
}

// ---- fused MLP: h2 = fp16( relu(aggx@W1 + b1) @ W2 ), per 64-node tile ----
__global__ __launch_bounds__(256) void k_mlp(
    const float* __restrict__ aggx, const float* __restrict__ W1,
    const float* __restrict__ b1, const float* __restrict__ W2,
    __half* __restrict__ h2, int N) {
    __shared__ float w1s[IN_CH * HID];   // 6 KiB
    __shared__ float ws[HID * OUTC];     // 32 KiB
    __shared__ float axs[64 * IN_CH];    // 3 KiB
    __shared__ float hs[64 * PADK];      // 33.8 KiB
    int t = threadIdx.x;
    for (int i = t; i < (HID * OUTC) / 4; i += 256)
        ((float4*)ws)[i] = ((const float4*)W2)[i];
    for (int i = t; i < IN_CH * HID; i += 256) w1s[i] = W1[i];
    long long base = (long long)blockIdx.x * 64;
    for (int i = t; i < 64 * IN_CH; i += 256) {
        long long n = base + i / IN_CH;
        axs[i] = (n < N) ? aggx[base * IN_CH + i] : 0.0f;
    }
    __syncthreads();
    {
        int k    = t & 127;
        int half = t >> 7;
        float w[IN_CH];
#pragma unroll
        for (int j = 0; j < IN_CH; ++j) w[j] = w1s[j * HID + k];
        float bb = b1[k];
        for (int r = 0; r < 32; ++r) {
            int row = half * 32 + r;
            float acc = bb;
#pragma unroll
            for (int j = 0; j < IN_CH; ++j)
                acc = fmaf(axs[row * IN_CH + j], w[j], acc);
            hs[row * PADK + k] = fmaxf(acc, 0.0f);
        }
    }
    __syncthreads();
    int tc = t & 15;
    int tr = t >> 4;
    float acc[4][4] = {};
    const float* ar = hs + 4 * tr * PADK;
#pragma unroll 8
    for (int k = 0; k < HID; k += 4) {
        float4 a[4], w[4];
#pragma unroll
        for (int j = 0; j < 4; ++j) a[j] = *(const float4*)(ar + j * PADK + k);
#pragma unroll
        for (int kk = 0; kk < 4; ++kk) w[kk] = *(const float4*)(ws + (k + kk) * OUTC + 4 * tc);
#pragma unroll
        for (int kk = 0; kk < 4; ++kk) {
            float aw[4] = {w[kk].x, w[kk].y, w[kk].z, w[kk].w};
#pragma unroll
            for (int j = 0; j < 4; ++j) {
                float av = (kk == 0) ? a[j].x : (kk == 1) ? a[j].y : (kk == 2) ? a[j].z : a[j].w;
                acc[j][0] = fmaf(av, aw[0], acc[j][0]);
                acc[j][1] = fmaf(av, aw[1], acc[j][1]);
                acc[j][2] = fmaf(av, aw[2], acc[j][2]);
                acc[j][3] = fmaf(av, aw[3], acc[j][3]);
            }
        }
    }
#pragma unroll
    for (int j = 0; j < 4; ++j) {
        long long r = base + 4 * tr + j;
        if (r < N) {
            __half2* d = (__half2*)(h2 + r * OUTC + 4 * tc);
            d[0] = __floats2half2_rn(acc[j][0], acc[j][1]);
            d[1] = __floats2half2_rn(acc[j][2], acc[j][3]);
        }
    }
}

// ---- layer 2 gather: out = A_norm·h2 + b2 (64 ch, fp16 h2, 8-deep pipe) ----
// nt loads on rs + nt stores on out: protect the 12.8MB h2 set in L2.
__global__ __launch_bounds__(256) void k_gather2(
    const int* __restrict__ start, const float* __restrict__ dinv,
    const int* __restrict__ rs, const __half* __restrict__ h2,
    const float* __restrict__ b2, float* __restrict__ out, int N) {
    int ln = threadIdx.x >> 6;
    int c  = threadIdx.x & 63;
    int n  = blockIdx.x * 4 + ln;
    if (n >= N) return;
    float dv = dinv[n];
    int s0 = start[n], k = start[n + 1] - s0;
    float acc = fmaf(__half2float(h2[(size_t)n * OUTC + c]), dv * dv, b2[c]);
    int j = 0;
    for (; j + 8 <= k; j += 8) {
        int r[8];
#pragma unroll
        for (int q = 0; q < 8; ++q) r[q] = __builtin_nontemporal_load(rs + s0 + j + q);
        float nm[8], vv[8];
#pragma unroll
        for (int q = 0; q < 8; ++q) nm[q] = dinv[r[q]] * dv;
#pragma unroll
        for (int q = 0; q < 8; ++q) vv[q] = __half2float(h2[(size_t)r[q] * OUTC + c]);
#pragma unroll
        for (int q = 0; q < 8; ++q) acc = fmaf(vv[q], nm[q], acc);
    }
    for (; j + 4 <= k; j += 4) {
        int r0 = rs[s0 + j], r1 = rs[s0 + j + 1], r2 = rs[s0 + j + 2], r3 = rs[s0 + j + 3];
        float n0 = dinv[r0] * dv, n1 = dinv[r1] * dv, n2 = dinv[r2] * dv, n3 = dinv[r3] * dv;
        float v0 = __half2float(h2[(size_t)r0 * OUTC + c]);
        float v1 = __half2float(h2[(size_t)r1 * OUTC + c]);
        float v2 = __half2float(h2[(size_t)r2 * OUTC + c]);
        float v3 = __half2float(h2[(size_t)r3 * OUTC + c]);
        acc = fmaf(v0, n0, acc); acc = fmaf(v1, n1, acc);
        acc = fmaf(v2, n2, acc); acc = fmaf(v3, n3, acc);
    }
    for (; j < k; ++j) {
        int r = rs[s0 + j];
        acc = fmaf(__half2float(h2[(size_t)r * OUTC + c]), dinv[r] * dv, acc);
    }
    __builtin_nontemporal_store(acc, out + (size_t)n * OUTC + c);
}

extern "C" void kernel_launch(void* const* d_in, const int* in_sizes, int n_in,
                              void* d_out, int out_size, void* d_ws, size_t ws_size,
                              hipStream_t stream) {
    const float* x  = (const float*)d_in[0];
    const int*   ei = (const int*)d_in[1];
    const float* W1 = (const float*)d_in[2];
    const float* b1 = (const float*)d_in[3];
    const float* W2 = (const float*)d_in[4];
    const float* b2 = (const float*)d_in[5];
    float* out = (float*)d_out;

    const int N = in_sizes[0] / IN_CH;
    const int E = in_sizes[1] / 2;
    const int* row = ei;
    const int* col = ei + E;
    const int NB = (N + 127) >> BSH;  // 782 for N=100000 (<= NBMAX)

    char* ws = (char*)d_ws;
    int*    bcnt   = (int*)ws;                      // NB (zeroed by k_init)
    int*    bstart = bcnt + NBMAX;                  // NB+1
    int*    gcur   = bstart + NBMAX + 8;            // NB
    int*    start  = gcur + NBMAX;                  // N+1
    float*  dinv   = (float*)(start + N + 8);       // N
    char*   p      = (char*)(dinv + N);
    p = (char*)(((uintptr_t)p + 255) & ~(uintptr_t)255);
    int*    bbuf   = (int*)p;                       // E packed ints (6.4 MB)
    int*    rs     = bbuf + E;                      // E ints (6.4 MB)
    __half* x16    = (__half*)(rs + E);             // N*12 fp16
    float*  aggx   = (float*)(x16 + (size_t)N * IN_CH + 8);   // N*12 f32
    __half* h2     = (__half*)(aggx + (size_t)N * IN_CH);     // N*64 fp16

    const int nchunks = (E + CHUNK - 1) / CHUNK;

    k_init<<<(N * IN_CH + 255) / 256, 256, 0, stream>>>(bcnt, NB, x, x16, N * IN_CH);
    k_bhist<<<nchunks, 256, 0, stream>>>(col, bcnt, E, NB);
    k_bscan<<<1, 256, 0, stream>>>(bcnt, bstart, gcur, start + N, E, NB);
    k_bucket<<<nchunks, 256, 0, stream>>>(row, col, gcur, bbuf, E, NB);
    k_csr<<<NB, 256, 0, stream>>>(bstart, bbuf, start, dinv, rs, N);

    k_gather_x<<<(N + 15) / 16, 192, 0, stream>>>(start, dinv, rs, x16, aggx, N);
    k_mlp<<<(N + 63) / 64, 256, 0, stream>>>(aggx, W1, b1, W2, h2, N);
    k_gather2<<<(N + 3) / 4, 256, 0, stream>>>(start, dinv, rs, h2, b2, out, N);
}

// Round 16
// 181.231 us; speedup vs baseline: 1.1056x; 1.1056x over previous
//
#include <hip/hip_runtime.h>
#include <hip/hip_fp16.h>

// 2-layer GCN, CSR-gather formulation (no float atomics).
// A_norm·(x@W1) = (A_norm·x)@W1 -> layer-1 aggregation in 12-ch space.
// CSR built by two-level LDS bucket sort (run-coalesced writes; scattered
// single-pass fill measured sector-bound at 64B/edge in r4/r7/r8).
// bbuf packed: (row<<7)|local_col (row < 2^17). rs payload = row only.
// RACE LESSON (r11): gather source values (dinv/x) must come from a PRIOR kernel.
// LAYOUT LESSON (r13): channel-slicing h2 trades traffic for 3x instructions.
// NT LESSON (r8/r15): nontemporal hints net-negative here (both directions).
// gather2: 2 nodes/wave, half2 channels -> per-edge issue count halved (r16).
// x and h2 in fp16 (measured safe r8-r15). MLP fused per 64-node tile.

#define IN_CH 12
#define HID 128
#define OUTC 64
#define PADK 132   // hidden-tile row stride in floats (breaks pow2 bank stride)
#define BSH 7      // bucket = 128 dest nodes
#define NBMAX 1024 // supports N <= 131072
#define CHUNK 4096 // edges per k_bucket block
#define SORTMAX 4096

// fused init: zero bcnt + convert x -> fp16
__global__ void k_init(int* __restrict__ bcnt, int nb,
                       const float* __restrict__ x, __half* __restrict__ x16, int n) {
    int i = blockIdx.x * blockDim.x + threadIdx.x;
    if (i < nb) bcnt[i] = 0;
    if (i < n) x16[i] = __float2half(x[i]);
}

// ---- CSR build pass 1: bucket histogram (LDS-privatized) ----
__global__ __launch_bounds__(256) void k_bhist(
    const int* __restrict__ col, int* __restrict__ bcnt, int E, int NB) {
    __shared__ int lh[NBMAX];
    int t = threadIdx.x;
    for (int i = t; i < NB; i += 256) lh[i] = 0;
    __syncthreads();
    int base = blockIdx.x * CHUNK;
    int end = min(base + CHUNK, E);
    for (int e = base + t; e < end; e += 256)
        atomicAdd(&lh[col[e] >> BSH], 1);
    __syncthreads();
    for (int i = t; i < NB; i += 256)
        if (lh[i]) atomicAdd(&bcnt[i], lh[i]);
}

// ---- pass 2: scan bucket counts -> bstart, gcur; also start[N]=E ----
__global__ __launch_bounds__(256) void k_bscan(
    const int* __restrict__ bcnt, int* __restrict__ bstart,
    int* __restrict__ gcur, int* __restrict__ startN, int E, int NB) {
    __shared__ int part[256];
    int t = threadIdx.x;
    int v[4]; int s = 0;
#pragma unroll
    for (int j = 0; j < 4; ++j) { int b = t * 4 + j; v[j] = (b < NB) ? bcnt[b] : 0; s += v[j]; }
    part[t] = s;
    __syncthreads();
    for (int off = 1; off < 256; off <<= 1) {
        int u = (t >= off) ? part[t - off] : 0;
        __syncthreads();
        part[t] += u;
        __syncthreads();
    }
    int base = (t > 0) ? part[t - 1] : 0;
#pragma unroll
    for (int j = 0; j < 4; ++j) {
        int b = t * 4 + j;
        if (b < NB) { bstart[b] = base; gcur[b] = base; }
        base += v[j];
    }
    if (t == 255) bstart[NB] = base;  // == E
    if (t == 0) *startN = E;          // start[N] = E
}

// ---- pass 3: LDS-staged bucket append; writes packed (row<<7)|lcol ----
__global__ __launch_bounds__(256) void k_bucket(
    const int* __restrict__ row, const int* __restrict__ col,
    int* __restrict__ gcur, int* __restrict__ bbuf, int E, int NB) {
    __shared__ int lh[NBMAX], lstart[NBMAX], lcur[NBMAX], gb[NBMAX];
    __shared__ int part[256];
    __shared__ int2 lbuf[CHUNK];  // 32 KiB
    int t = threadIdx.x;
    for (int i = t; i < NB; i += 256) lh[i] = 0;
    __syncthreads();
    int base0 = blockIdx.x * CHUNK;
    int end = min(base0 + CHUNK, E);
    for (int e = base0 + t; e < end; e += 256)
        atomicAdd(&lh[col[e] >> BSH], 1);
    __syncthreads();
    int v[4]; int s = 0;
#pragma unroll
    for (int j = 0; j < 4; ++j) { int b = t * 4 + j; v[j] = (b < NB) ? lh[b] : 0; s += v[j]; }
    part[t] = s;
    __syncthreads();
    for (int off = 1; off < 256; off <<= 1) {
        int u = (t >= off) ? part[t - off] : 0;
        __syncthreads();
        part[t] += u;
        __syncthreads();
    }
    int pb = (t > 0) ? part[t - 1] : 0;
#pragma unroll
    for (int j = 0; j < 4; ++j) {
        int b = t * 4 + j;
        if (b < NB) lstart[b] = pb;
        pb += v[j];
    }
    __syncthreads();
    for (int i = t; i < NB; i += 256) {
        int c = lh[i];
        gb[i] = c ? atomicAdd(&gcur[i], c) : 0;
        lcur[i] = lstart[i];
    }
    __syncthreads();
    for (int e = base0 + t; e < end; e += 256) {
        int c = col[e];
        int p = atomicAdd(&lcur[c >> BSH], 1);
        lbuf[p] = make_int2(row[e], c);
    }
    __syncthreads();
    int cN = end - base0;
    for (int i = t; i < cN; i += 256) {
        int2 rc = lbuf[i];
        int b = rc.y >> BSH;
        bbuf[gb[b] + (i - lstart[b])] = (rc.x << BSH) | (rc.y & 127);
    }
}

// ---- pass 4: per-bucket CSR: start/dinv + LDS sort -> coalesced rs write ----
__global__ __launch_bounds__(256) void k_csr(
    const int* __restrict__ bstart, const int* __restrict__ bbuf,
    int* __restrict__ start, float* __restrict__ dinv,
    int* __restrict__ rs, int N) {
    int me = blockIdx.x;
    int lo = me << BSH;
    int bs = bstart[me], be = bstart[me + 1];
    int cntb = be - bs;
    __shared__ int lh[128], lsc[128];
    __shared__ int lsort[SORTMAX];  // 16 KiB
    int t = threadIdx.x;
    bool lds_ok = (cntb <= SORTMAX);
    if (t < 128) lh[t] = 0;
    __syncthreads();
    for (int i = t; i < cntb; i += 256)
        atomicAdd(&lh[bbuf[bs + i] & 127], 1);
    __syncthreads();
    if (t < 128) lsc[t] = lh[t];
    __syncthreads();
    for (int off = 1; off < 128; off <<= 1) {
        int u = (t < 128 && t >= off) ? lsc[t - off] : 0;
        __syncthreads();
        if (t < 128) lsc[t] += u;
        __syncthreads();
    }
    if (t < 128) {
        int excl = lsc[t] - lh[t];
        int n = lo + t;
        if (n < N) {
            start[n] = bs + excl;
            dinv[n] = rsqrtf((float)lh[t] + 1.0f);
        }
        lsc[t] = excl;  // reuse as cursor
    }
    __syncthreads();
    for (int i = t; i < cntb; i += 256) {
        int v = bbuf[bs + i];
        int p = atomicAdd(&lsc[v & 127], 1);
        int r = v >> BSH;
        if (lds_ok) lsort[p] = r; else rs[bs + p] = r;
    }
    __syncthreads();
    if (lds_ok)  // coalesced rs write-out
        for (int i = t; i < cntb; i += 256) rs[bs + i] = lsort[i];
}

// ---- layer 1 gather: aggx = A_norm·x (12 ch, fp16 x, 8-deep pipeline) ----
__global__ __launch_bounds__(192) void k_gather_x(
    const int* __restrict__ start, const float* __restrict__ dinv,
    const int* __restrict__ rs, const __half* __restrict__ x16,
    float* __restrict__ aggx, int N) {
    int ln = threadIdx.x / 12;
    int c  = threadIdx.x % 12;
    int n  = blockIdx.x * 16 + ln;
    if (n >= N) return;
    float dv = dinv[n];
    int s0 = start[n], k = start[n + 1] - s0;
    float acc = __half2float(x16[(size_t)n * IN_CH + c]) * dv * dv;
    int j = 0;
    for (; j + 8 <= k; j += 8) {
        int r[8];
#pragma unroll
        for (int q = 0; q < 8; ++q) r[q] = rs[s0 + j + q];
        float nm[8], vv[8];
#pragma unroll
        for (int q = 0; q < 8; ++q) nm[q] = dinv[r[q]] * dv;
#pragma unroll
        for (int q = 0; q < 8; ++q) vv[q] = __half2float(x16[(size_t)r[q] * IN_CH + c]);
#pragma unroll
        for (int q = 0; q < 8; ++q) acc = fmaf(vv[q], nm[q], acc);
    }
    for (; j + 4 <= k; j += 4) {
        int r0 = rs[s0 + j], r1 = rs[s0 + j + 1], r2 = rs[s0 + j + 2], r3 = rs[s0 + j + 3];
        float n0 = dinv[r0] * dv, n1 = dinv[r1] * dv, n2 = dinv[r2] * dv, n3 = dinv[r3] * dv;
        float v0 = __half2float(x16[(size_t)r0 * IN_CH + c]);
        float v1 = __half2float(x16[(size_t)r1 * IN_CH + c]);
        float v2 = __half2float(x16[(size_t)r2 * IN_CH + c]);
        float v3 = __half2float(x16[(size_t)r3 * IN_CH + c]);
        acc = fmaf(v0, n0, acc); acc = fmaf(v1, n1, acc);
        acc = fmaf(v2, n2, acc); acc = fmaf(v3, n3, acc);
    }
    for (; j < k; ++j) {
        int r = rs[s0 + j];
        acc = fmaf(__half2float(x16[(size_t)r * IN_CH + c]), dinv[r] * dv, acc);
    }
    aggx[(size_t)n * IN_CH + c] = acc;
}

// ---- fused MLP: h2 = fp16( relu(aggx@W1 + b1) @ W2 ), per 64-node tile ----
__global__ __launch_bounds__(256) void k_mlp(
    const float* __restrict__ aggx, const float* __restrict__ W1,
    const float* __restrict__ b1, const float* __restrict__ W2,
    __half* __restrict__ h2, int N) {
    __shared__ float w1s[IN_CH * HID];   // 6 KiB
    __shared__ float ws[HID * OUTC];     // 32 KiB
    __shared__ float axs[64 * IN_CH];    // 3 KiB
    __shared__ float hs[64 * PADK];      // 33.8 KiB
    int t = threadIdx.x;
    for (int i = t; i < (HID * OUTC) / 4; i += 256)
        ((float4*)ws)[i] = ((const float4*)W2)[i];
    for (int i = t; i < IN_CH * HID; i += 256) w1s[i] = W1[i];
    long long base = (long long)blockIdx.x * 64;
    for (int i = t; i < 64 * IN_CH; i += 256) {
        long long n = base + i / IN_CH;
        axs[i] = (n < N) ? aggx[base * IN_CH + i] : 0.0f;
    }
    __syncthreads();
    {
        int k    = t & 127;
        int half = t >> 7;
        float w[IN_CH];
#pragma unroll
        for (int j = 0; j < IN_CH; ++j) w[j] = w1s[j * HID + k];
        float bb = b1[k];
        for (int r = 0; r < 32; ++r) {
            int row = half * 32 + r;
            float acc = bb;
#pragma unroll
            for (int j = 0; j < IN_CH; ++j)
                acc = fmaf(axs[row * IN_CH + j], w[j], acc);
            hs[row * PADK + k] = fmaxf(acc, 0.0f);
        }
    }
    __syncthreads();
    int tc = t & 15;
    int tr = t >> 4;
    float acc[4][4] = {};
    const float* ar = hs + 4 * tr * PADK;
#pragma unroll 8
    for (int k = 0; k < HID; k += 4) {
        float4 a[4], w[4];
#pragma unroll
        for (int j = 0; j < 4; ++j) a[j] = *(const float4*)(ar + j * PADK + k);
#pragma unroll
        for (int kk = 0; kk < 4; ++kk) w[kk] = *(const float4*)(ws + (k + kk) * OUTC + 4 * tc);
#pragma unroll
        for (int kk = 0; kk < 4; ++kk) {
            float aw[4] = {w[kk].x, w[kk].y, w[kk].z, w[kk].w};
#pragma unroll
            for (int j = 0; j < 4; ++j) {
                float av = (kk == 0) ? a[j].x : (kk == 1) ? a[j].y : (kk == 2) ? a[j].z : a[j].w;
                acc[j][0] = fmaf(av, aw[0], acc[j][0]);
                acc[j][1] = fmaf(av, aw[1], acc[j][1]);
                acc[j][2] = fmaf(av, aw[2], acc[j][2]);
                acc[j][3] = fmaf(av, aw[3], acc[j][3]);
            }
        }
    }
#pragma unroll
    for (int j = 0; j < 4; ++j) {
        long long r = base + 4 * tr + j;
        if (r < N) {
            __half2* d = (__half2*)(h2 + r * OUTC + 4 * tc);
            d[0] = __floats2half2_rn(acc[j][0], acc[j][1]);
            d[1] = __floats2half2_rn(acc[j][2], acc[j][3]);
        }
    }
}

// ---- layer 2 gather: out = A_norm·h2 + b2 ----
// 2 nodes per wave (half-wave each), 2 channels per lane via half2:
// per-edge wave-issue count halved vs 1-node/wave; h2 reads stay coalesced.
__global__ __launch_bounds__(256) void k_gather2(
    const int* __restrict__ start, const float* __restrict__ dinv,
    const int* __restrict__ rs, const __half* __restrict__ h2,
    const float* __restrict__ b2, float* __restrict__ out, int N) {
    int n = blockIdx.x * 8 + (threadIdx.x >> 5);  // 8 nodes per 256-thr block
    if (n >= N) return;
    int l = threadIdx.x & 31;                     // channels 2l, 2l+1
    const __half2* hv = (const __half2*)h2;       // 32 half2 per row
    float dv = dinv[n];
    int s0 = start[n], k = start[n + 1] - s0;
    float2 bb = *(const float2*)(b2 + 2 * l);
    float2 hn = __half22float2(hv[(size_t)n * 32 + l]);
    float dvv = dv * dv;
    float ax = fmaf(hn.x, dvv, bb.x);
    float ay = fmaf(hn.y, dvv, bb.y);
    int j = 0;
    for (; j + 8 <= k; j += 8) {
        int r[8];
#pragma unroll
        for (int q = 0; q < 8; ++q) r[q] = rs[s0 + j + q];
        float nm[8];
#pragma unroll
        for (int q = 0; q < 8; ++q) nm[q] = dinv[r[q]] * dv;
        float2 vv[8];
#pragma unroll
        for (int q = 0; q < 8; ++q) vv[q] = __half22float2(hv[(size_t)r[q] * 32 + l]);
#pragma unroll
        for (int q = 0; q < 8; ++q) {
            ax = fmaf(vv[q].x, nm[q], ax);
            ay = fmaf(vv[q].y, nm[q], ay);
        }
    }
    for (; j + 4 <= k; j += 4) {
        int r0 = rs[s0 + j], r1 = rs[s0 + j + 1], r2 = rs[s0 + j + 2], r3 = rs[s0 + j + 3];
        float n0 = dinv[r0] * dv, n1 = dinv[r1] * dv, n2 = dinv[r2] * dv, n3 = dinv[r3] * dv;
        float2 v0 = __half22float2(hv[(size_t)r0 * 32 + l]);
        float2 v1 = __half22float2(hv[(size_t)r1 * 32 + l]);
        float2 v2 = __half22float2(hv[(size_t)r2 * 32 + l]);
        float2 v3 = __half22float2(hv[(size_t)r3 * 32 + l]);
        ax = fmaf(v0.x, n0, ax); ay = fmaf(v0.y, n0, ay);
        ax = fmaf(v1.x, n1, ax); ay = fmaf(v1.y, n1, ay);
        ax = fmaf(v2.x, n2, ax); ay = fmaf(v2.y, n2, ay);
        ax = fmaf(v3.x, n3, ax); ay = fmaf(v3.y, n3, ay);
    }
    for (; j < k; ++j) {
        int r = rs[s0 + j];
        float nm = dinv[r] * dv;
        float2 vv = __half22float2(hv[(size_t)r * 32 + l]);
        ax = fmaf(vv.x, nm, ax);
        ay = fmaf(vv.y, nm, ay);
    }
    *(float2*)(out + (size_t)n * OUTC + 2 * l) = make_float2(ax, ay);
}

extern "C" void kernel_launch(void* const* d_in, const int* in_sizes, int n_in,
                              void* d_out, int out_size, void* d_ws, size_t ws_size,
                              hipStream_t stream) {
    const float* x  = (const float*)d_in[0];
    const int*   ei = (const int*)d_in[1];
    const float* W1 = (const float*)d_in[2];
    const float* b1 = (const float*)d_in[3];
    const float* W2 = (const float*)d_in[4];
    const float* b2 = (const float*)d_in[5];
    float* out = (float*)d_out;

    const int N = in_sizes[0] / IN_CH;
    const int E = in_sizes[1] / 2;
    const int* row = ei;
    const int* col = ei + E;
    const int NB = (N + 127) >> BSH;  // 782 for N=100000 (<= NBMAX)

    char* ws = (char*)d_ws;
    int*    bcnt   = (int*)ws;                      // NB (zeroed by k_init)
    int*    bstart = bcnt + NBMAX;                  // NB+1
    int*    gcur   = bstart + NBMAX + 8;            // NB
    int*    start  = gcur + NBMAX;                  // N+1
    float*  dinv   = (float*)(start + N + 8);       // N
    char*   p      = (char*)(dinv + N);
    p = (char*)(((uintptr_t)p + 255) & ~(uintptr_t)255);
    int*    bbuf   = (int*)p;                       // E packed ints (6.4 MB)
    int*    rs     = bbuf + E;                      // E ints (6.4 MB)
    __half* x16    = (__half*)(rs + E);             // N*12 fp16
    float*  aggx   = (float*)(x16 + (size_t)N * IN_CH + 8);   // N*12 f32
    __half* h2     = (__half*)(aggx + (size_t)N * IN_CH);     // N*64 fp16

    const int nchunks = (E + CHUNK - 1) / CHUNK;

    k_init<<<(N * IN_CH + 255) / 256, 256, 0, stream>>>(bcnt, NB, x, x16, N * IN_CH);
    k_bhist<<<nchunks, 256, 0, stream>>>(col, bcnt, E, NB);
    k_bscan<<<1, 256, 0, stream>>>(bcnt, bstart, gcur, start + N, E, NB);
    k_bucket<<<nchunks, 256, 0, stream>>>(row, col, gcur, bbuf, E, NB);
    k_csr<<<NB, 256, 0, stream>>>(bstart, bbuf, start, dinv, rs, N);

    k_gather_x<<<(N + 15) / 16, 192, 0, stream>>>(start, dinv, rs, x16, aggx, N);
    k_mlp<<<(N + 63) / 64, 256, 0, stream>>>(aggx, W1, b1, W2, h2, N);
    k_gather2<<<(N + 7) / 8, 256, 0, stream>>>(start, dinv, rs, h2, b2, out, N);
}